// Round 12
// baseline (6838.628 us; speedup 1.0000x reference)
//
#include <hip/hip_runtime.h>
#include <math.h>

// Problem constants: B=8, S=16, CIN=128, H=W=64, D=64
// Padded field layout for conv inputs: [b][c][66 rows][72 cols], value(x,y) at [y+1][x+4],
// borders zero. PF = 8*64*66*72 = 2,433,024 floats.

__device__ __forceinline__ float sigf(float x){ return 1.0f/(1.0f + expf(-x)); }

#define FMA4(A, W, V0, V1, V2, V3) { (A).x += (W)*(V0); (A).y += (W)*(V1); (A).z += (W)*(V2); (A).w += (W)*(V3); }

// ---------------------------------------------------------------------------
// reshape clstm_w (256,128,3,3) -> w5[(rk*2 + chh)*128 + w*16 + g*4 + c],
// rk = ic*9+k, oc_global = g*64 + chh*32 + w*4 + c.
// Wave w of block-half chh owns channels chh*32 + w*4 .. +4, all 4 gates.
__global__ __launch_bounds__(256) void k_w5(const float* __restrict__ cw, float* __restrict__ w5){
    int idx = blockIdx.x*256 + threadIdx.x;
    if (idx < 294912){
        int col = idx & 127;            // w*16 + g*4 + c
        int rkh = idx >> 7;             // rk*2 + chh
        int chh = rkh & 1, rk = rkh >> 1;
        int w = col >> 4, g = (col >> 2) & 3, c = col & 3;
        int oc = g*64 + chh*32 + w*4 + c;
        w5[idx] = cw[oc*1152 + rk];
    }
}

// ---------------------------------------------------------------------------
// 1x1 proj conv + BN partial sums. Writes raw t==0 slice into x0 buffer.
__global__ __launch_bounds__(256) void k_proj(const float* __restrict__ x, const float* __restrict__ pw,
                                              float* __restrict__ x0raw, float* __restrict__ psum,
                                              float* __restrict__ psumsq){
    __shared__ __align__(16) float smem[8192];
    const int tile = blockIdx.x;
    const int n    = blockIdx.y;
    const int tid  = threadIdx.x;
    const int pj = tid & 63, dg = tid >> 6;

    for (int r = tid; r < 8192; r += 256){
        int c = r >> 6, d = r & 63;
        smem[r] = pw[d*128 + c];
    }
    __syncthreads();

    const int p0 = tile*256 + pj*4;
    float4 acc[16];
#pragma unroll
    for (int i=0;i<16;i++) acc[i] = make_float4(0.f,0.f,0.f,0.f);

    const float* xb = x + (((size_t)n) << 19) + p0;
    for (int c = 0; c < 128; ++c){
        float4 xv = *(const float4*)(xb + ((size_t)c << 12));
        const float4* wr = (const float4*)(smem + c*64 + dg*16);
#pragma unroll
        for (int q=0;q<4;++q){
            float4 w4 = wr[q];
            FMA4(acc[q*4+0], w4.x, xv.x, xv.y, xv.z, xv.w);
            FMA4(acc[q*4+1], w4.y, xv.x, xv.y, xv.z, xv.w);
            FMA4(acc[q*4+2], w4.z, xv.x, xv.y, xv.z, xv.w);
            FMA4(acc[q*4+3], w4.w, xv.x, xv.y, xv.z, xv.w);
        }
    }

    const int t = n & 15, b = n >> 4;
    if (t == 0){
#pragma unroll
        for (int i=0;i<16;i++){
            int dd = dg*16 + i;
            *(float4*)(x0raw + (((size_t)(b*64 + dd)) << 12) + p0) = acc[i];
        }
    }
    float ls[16], lss[16];
#pragma unroll
    for (int i=0;i<16;i++){
        float4 a = acc[i];
        ls[i]  = a.x + a.y + a.z + a.w;
        lss[i] = a.x*a.x + a.y*a.y + a.z*a.z + a.w*a.w;
    }
    __syncthreads();
#pragma unroll
    for (int i=0;i<16;i++) smem[pj*65 + dg*16 + i] = ls[i];
    __syncthreads();
    if (tid < 64){
        float s = 0.f;
        for (int p=0;p<64;p++) s += smem[p*65 + tid];
        psum[((n*16 + tile) << 6) + tid] = s;
    }
    __syncthreads();
#pragma unroll
    for (int i=0;i<16;i++) smem[pj*65 + dg*16 + i] = lss[i];
    __syncthreads();
    if (tid < 64){
        float s = 0.f;
        for (int p=0;p<64;p++) s += smem[p*65 + tid];
        psumsq[((n*16 + tile) << 6) + tid] = s;
    }
}

// ---------------------------------------------------------------------------
__global__ __launch_bounds__(64) void k_bnfinal(const float* __restrict__ psum, const float* __restrict__ psumsq,
                                                const float* __restrict__ gamma, const float* __restrict__ beta,
                                                float* __restrict__ scale, float* __restrict__ shift,
                                                float* __restrict__ xmean){
    const int d = threadIdx.x;
    double gs = 0.0, gss = 0.0;
    for (int n=0;n<128;n++){
        float s = 0.f, ss = 0.f;
        for (int tl=0;tl<16;tl++){
            s  += psum  [((n*16+tl)<<6) + d];
            ss += psumsq[((n*16+tl)<<6) + d];
        }
        gs += (double)s; gss += (double)ss;
    }
    double mu  = gs  / 524288.0;
    double var = gss / 524288.0 - mu*mu;
    double sc  = (double)gamma[d] / sqrt(var + 1e-5);
    float scf = (float)sc;
    float shf = (float)((double)beta[d] - mu*sc);
    scale[d] = scf; shift[d] = shf;
    for (int n=0;n<128;n++){
        float s = 0.f;
        for (int tl=0;tl<16;tl++) s += psum[((n*16+tl)<<6) + d];
        xmean[(n<<6) + d] = (s * (1.f/4096.f)) * scf + shf;
    }
}

// ---------------------------------------------------------------------------
// Zero a float4-multiple region (yhat_p | hfA_p | hfB_p | cf, contiguous).
__global__ __launch_bounds__(256) void k_zero(float* __restrict__ z){
    size_t i = ((size_t)blockIdx.x*256 + threadIdx.x)*4;
    *(float4*)(z + i) = make_float4(0.f,0.f,0.f,0.f);
}

// ---------------------------------------------------------------------------
// Apply BN to x0 (in place), write yhat_p interior, init states, P=P_init.
__global__ __launch_bounds__(256) void k_init(const float* __restrict__ scale, const float* __restrict__ shift,
                                              float* __restrict__ x0, float* __restrict__ yhat_p,
                                              const float* __restrict__ Pinit, float* __restrict__ Pg,
                                              float* __restrict__ hQ, float* __restrict__ cQ,
                                              float* __restrict__ hR, float* __restrict__ cR){
    size_t idx = (size_t)blockIdx.x*256 + threadIdx.x;   // 2,097,152 total
    int d = (int)((idx >> 12) & 63);
    float v = x0[idx]*scale[d] + shift[d];
    x0[idx] = v;
    int b = (int)(idx >> 18), r = (int)((idx >> 6) & 63), xx = (int)(idx & 63);
    yhat_p[(((size_t)(b*64 + d))*66 + r + 1)*72 + xx + 4] = v;
    if (idx < 512){ hQ[idx]=0.f; cQ[idx]=0.f; hR[idx]=0.f; cR[idx]=0.f; }
    if (idx < 32768) Pg[idx] = Pinit[idx & 4095];
}

// ---------------------------------------------------------------------------
// ConvLSTM step. grid (64 rows, 2 ch-halves, 8 b) = 1024 blocks of 512 thr
// -> 4 blocks/CU = 8 waves/SIMD (full grid occupancy).
// Wave-uniform scalar weights (round-11 win): lane = px, wave w owns channels
// chh*32 + w*4 .. +4 (all 4 gates) -> acc[4][4] = 16 floats, in-reg gating.
// 8 chunks of 16 ic; input staging double-buffered (2 float4/thread register
// prefetch), 1 barrier per chunk. hfpart via wave shuffle-reduce (no LDS).
// No y_tick tail: fcf folded into k_small/k_apply algebraically.
__global__ __launch_bounds__(512) void k_conv(const float* __restrict__ yhat_p, const float* __restrict__ hfin_p,
                                              float* __restrict__ hfout_p, float* __restrict__ cf,
                                              const float* __restrict__ w5, const float* __restrict__ cb,
                                              float* __restrict__ hfpart){
    __shared__ __align__(16) float smem[6912];   // 2 x 3456 (16 ic x 3 r x 72)
    const int row = blockIdx.x;
    const int chh = blockIdx.y;
    const int b   = blockIdx.z;
    const int tid = threadIdx.x;
    const int px  = tid & 63;
    const int w   = __builtin_amdgcn_readfirstlane(tid >> 6);   // wave-uniform
    const int c0  = chh*32 + w*4;

    float acc[4][4];
#pragma unroll
    for (int g=0;g<4;++g)
#pragma unroll
        for (int c=0;c<4;++c) acc[g][c] = 0.f;

    // staging: 864 float4 slots (16 icl x 3 r x 18 x4); thread covers slot tid
    // and (tid+512 if tid<352).
    int s_icl0, s_r0, s_x40, s_icl1=0, s_r1=0, s_x41=0;
    { int s = tid; s_icl0 = s/54; int rem = s - s_icl0*54; s_r0 = rem/18; s_x40 = rem - s_r0*18; }
    const bool has1 = (tid < 352);
    if (has1){ int s = tid + 512; s_icl1 = s/54; int rem = s - s_icl1*54; s_r1 = rem/18; s_x41 = rem - s_r1*18; }

    float4 pf0, pf1;
    auto issue = [&](int icc){
        { int ic = icc*16 + s_icl0; const float* f = (ic < 64) ? yhat_p : hfin_p;
          pf0 = *(const float4*)(f + (((size_t)(b*64 + (ic & 63)))*66 + row + s_r0)*72 + s_x40*4); }
        if (has1){ int ic = icc*16 + s_icl1; const float* f = (ic < 64) ? yhat_p : hfin_p;
          pf1 = *(const float4*)(f + (((size_t)(b*64 + (ic & 63)))*66 + row + s_r1)*72 + s_x41*4); }
    };
    auto commit = [&](int buf){
        *(float4*)(smem + buf*3456 + tid*4) = pf0;
        if (has1) *(float4*)(smem + buf*3456 + (tid+512)*4) = pf1;
    };

    issue(0); commit(0); __syncthreads();
    int p = 0;
    for (int icc = 0; icc < 8; ++icc){
        if (icc < 7) issue(icc+1);          // global loads in flight under compute
        const float* ib0 = smem + p*3456;
#pragma unroll 2
        for (int icl = 0; icl < 16; ++icl){
            const float* ib = ib0 + icl*216 + px + 3;
            const float v0 = ib[0],   v1 = ib[1],   v2 = ib[2];
            const float v3 = ib[72],  v4 = ib[73],  v5 = ib[74];
            const float v6 = ib[144], v7 = ib[145], v8 = ib[146];
            const int rk = (icc*16 + icl)*9;
#define WG(KI, VAL) { const float* q_ = w5 + ((((size_t)(rk+(KI)))*2 + chh) << 7) + w*16; \
    _Pragma("unroll") for (int g=0;g<4;++g) \
    _Pragma("unroll") for (int c=0;c<4;++c) acc[g][c] += q_[g*4+c]*(VAL); }
            WG(0,v0) WG(1,v1) WG(2,v2)
            WG(3,v3) WG(4,v4) WG(5,v5)
            WG(6,v6) WG(7,v7) WG(8,v8)
#undef WG
        }
        if (icc < 7) commit(p^1);           // vmcnt drained here, hidden by compute
        __syncthreads();
        p ^= 1;
    }

    // ---- gating fully in registers (gate order i,f,o,g) ----
#pragma unroll
    for (int c=0;c<4;++c){
        const int d = c0 + c;
        float zi = acc[0][c] + cb[d];
        float zf = acc[1][c] + cb[64+d];
        float zo = acc[2][c] + cb[128+d];
        float zg = acc[3][c] + cb[192+d];
        const size_t gidx = (((size_t)(b*64 + d)) << 12) + row*64 + px;
        float c_old = cf[gidx];
        float c2 = sigf(zf)*c_old + sigf(zi)*tanhf(zg);
        float hh = sigf(zo)*tanhf(c2);
        cf[gidx] = c2;
        hfout_p[(((size_t)(b*64 + d))*66 + row + 1)*72 + px + 4] = hh;
        float hs = hh;
        for (int off=32; off; off >>= 1) hs += __shfl_down(hs, off);
        if (px == 0) hfpart[((b*64 + row) << 6) + d] = hs;
    }
}

// ---------------------------------------------------------------------------
// Per-step small ops + Kalman update + M=(I-K)fcf_w, v0=(I-K)fcf_b.
// grid 8 (b), block 256. ytm computed algebraically from hfm (mean is linear).
__global__ __launch_bounds__(256) void k_small(int t,
        const float* __restrict__ hfpart, const float* __restrict__ xmean,
        const float* __restrict__ fcf_w, const float* __restrict__ fcf_b,
        const float* __restrict__ fcF_w, const float* __restrict__ fcF_b,
        const float* __restrict__ lq_wih, const float* __restrict__ lq_whh,
        const float* __restrict__ lq_bih, const float* __restrict__ lq_bhh,
        const float* __restrict__ lr_wih, const float* __restrict__ lr_whh,
        const float* __restrict__ lr_bih, const float* __restrict__ lr_bhh,
        const float* __restrict__ fcQ_w, const float* __restrict__ fcQ_b,
        const float* __restrict__ fcR_w, const float* __restrict__ fcR_b,
        float* __restrict__ hQ, float* __restrict__ cQ, float* __restrict__ hR, float* __restrict__ cR,
        float* __restrict__ Pg, float* __restrict__ Kg,
        float* __restrict__ Mg, float* __restrict__ v0g){
    const int b = blockIdx.x, tid = threadIdx.x;
    __shared__ __align__(16) float aug[64*132];
    __shared__ __align__(16) float Pl[4096];
    __shared__ float hfm[64], ytm[64], xm[64], Fv[64], Qd[64], Rd[64], rds[64], fb_s[64];
    __shared__ float hq_s[64], cq_s[64], hr_s[64], cr_s[64];
    __shared__ float gq[256], gr[256];

    if (tid < 64){
        float s = 0.f;
        for (int r=0;r<64;r++) s += hfpart[((b*64 + r) << 6) + tid];
        hfm[tid] = s * (1.f/4096.f);
        xm[tid] = xmean[((b*16 + t) << 6) + tid];
        hq_s[tid] = hQ[b*64+tid]; cq_s[tid] = cQ[b*64+tid];
        hr_s[tid] = hR[b*64+tid]; cr_s[tid] = cR[b*64+tid];
        fb_s[tid] = fcf_b[tid];
    }
    __syncthreads();
    if (tid < 64){   // ytm = fcf_b + fcf_w . hfm ; Fv = fcF_b + fcF_w . hfm
        float a = fb_s[tid], a2 = fcF_b[tid];
        for (int e=0;e<64;e++){
            a  += fcf_w[tid*64+e]*hfm[e];
            a2 += fcF_w[tid*64+e]*hfm[e];
        }
        ytm[tid] = a; Fv[tid] = a2;
    }
    __syncthreads();
    {
        int j = tid;
        float aq = lq_bih[j] + lq_bhh[j];
        float ar = lr_bih[j] + lr_bhh[j];
        for (int e=0;e<64;e++){
            aq += lq_wih[j*64+e]*ytm[e] + lq_whh[j*64+e]*hq_s[e];
            ar += lr_wih[j*64+e]*xm[e]  + lr_whh[j*64+e]*hr_s[e];
        }
        gq[j] = aq; gr[j] = ar;
    }
    __syncthreads();
    if (tid < 64){   // lstm_cell gate order: i, f, g, o
        int dd = tid;
        float gi = gq[dd], gf = gq[64+dd], gg = gq[128+dd], go = gq[192+dd];
        float c2 = sigf(gf)*cq_s[dd] + sigf(gi)*tanhf(gg);
        float h2 = sigf(go)*tanhf(c2);
        cq_s[dd] = c2; hq_s[dd] = h2;
        gi = gr[dd]; gf = gr[64+dd]; gg = gr[128+dd]; go = gr[192+dd];
        c2 = sigf(gf)*cr_s[dd] + sigf(gi)*tanhf(gg);
        h2 = sigf(go)*tanhf(c2);
        cr_s[dd] = c2; hr_s[dd] = h2;
    }
    __syncthreads();
    if (tid < 64){
        float aq_ = fcQ_b[tid], ar_ = fcR_b[tid];
        for (int e=0;e<64;e++){ aq_ += fcQ_w[tid*64+e]*hq_s[e]; ar_ += fcR_w[tid*64+e]*hr_s[e]; }
        Qd[tid] = expf(aq_); Rd[tid] = expf(ar_);
        hQ[b*64+tid] = hq_s[tid]; cQ[b*64+tid] = cq_s[tid];
        hR[b*64+tid] = hr_s[tid]; cR[b*64+tid] = cr_s[tid];
    }
    __syncthreads();
    // P = P*FF + diag(Qd); aug = [A=P+diag(Rd) | P]
    for (int r = tid; r < 4096; r += 256){
        int i = r >> 6, j = r & 63;
        float p = Pg[((size_t)b << 12) + r] * Fv[i]*Fv[j] + (i==j ? Qd[i] : 0.f);
        Pl[r] = p;
        aug[i*132 + 64 + j] = p;
        aug[i*132 + j]      = p + (i==j ? Rd[i] : 0.f);
    }
    __syncthreads();
    const int r_ = tid & 63, cq_ = tid >> 6;
    for (int k = 0; k < 64; ++k){
        float akk = aug[k*132 + k];
        float f = aug[r_*132 + k] / akk;
        if (r_ != k){
#pragma unroll
            for (int u = 0; u < 8; ++u){
                int c4 = cq_*32 + u*4;
                if (c4 + 3 > k){
                    float4 pv = *(const float4*)(aug + k*132 + c4);
                    float4 av = *(const float4*)(aug + r_*132 + c4);
                    av.x = (c4+0 > k) ? av.x - f*pv.x : av.x;
                    av.y = (c4+1 > k) ? av.y - f*pv.y : av.y;
                    av.z = (c4+2 > k) ? av.z - f*pv.z : av.z;
                    av.w = (c4+3 > k) ? av.w - f*pv.w : av.w;
                    *(float4*)(aug + r_*132 + c4) = av;
                }
            }
        }
        __syncthreads();
    }
    if (tid < 64) rds[tid] = 1.0f / aug[tid*132 + tid];
    __syncthreads();
    // T1 = (I-K)P  into aug left half
    {
        const int i = tid >> 2, jq = tid & 3;
        float4 tv[4];
#pragma unroll
        for (int q=0;q<4;++q) tv[q] = *(const float4*)(Pl + i*64 + jq*16 + q*4);
        for (int m=0;m<64;++m){
            float kim = aug[m*132 + 64 + i] * rds[m];
#pragma unroll
            for (int q=0;q<4;++q){
                float4 pv = *(const float4*)(Pl + m*64 + jq*16 + q*4);
                tv[q].x -= kim*pv.x; tv[q].y -= kim*pv.y; tv[q].z -= kim*pv.z; tv[q].w -= kim*pv.w;
            }
        }
#pragma unroll
        for (int q=0;q<4;++q) *(float4*)(aug + i*132 + jq*16 + q*4) = tv[q];
    }
    __syncthreads();
    // P_new = T1 - T1*K^T + K*diag(Rd)*K^T ; emit K
    {
        const int i = tid >> 2, jq = tid & 3;
        float4 a2[4];
#pragma unroll
        for (int q=0;q<4;++q) a2[q] = *(const float4*)(aug + i*132 + jq*16 + q*4);
        for (int m=0;m<64;++m){
            float t1im = aug[i*132 + m];
            float kim  = aug[m*132 + 64 + i] * rds[m];
            float coef = rds[m] * (kim * Rd[m] - t1im);
#pragma unroll
            for (int q=0;q<4;++q){
                float4 yv = *(const float4*)(aug + m*132 + 64 + jq*16 + q*4);
                a2[q].x += coef*yv.x; a2[q].y += coef*yv.y; a2[q].z += coef*yv.z; a2[q].w += coef*yv.w;
            }
        }
        size_t base = ((size_t)b << 12) + (size_t)i*64;
#pragma unroll
        for (int q=0;q<4;++q) *(float4*)(Pg + base + jq*16 + q*4) = a2[q];
#pragma unroll
        for (int q=0;q<4;++q){
#pragma unroll
            for (int e=0;e<4;++e){
                int j = jq*16 + q*4 + e;
                Kg[base + j] = aug[j*132 + 64 + i] * rds[j];
            }
        }
    }
    __syncthreads();
    // stage fcf_w into Pl (row-major), then M = (I-K)fcf_w, v0 = (I-K)fcf_b
    for (int r = tid; r < 4096; r += 256) Pl[r] = fcf_w[r];
    __syncthreads();
    {
        const int i = tid >> 2, jq = tid & 3;
        float4 m4[4];
#pragma unroll
        for (int q=0;q<4;++q) m4[q] = *(const float4*)(Pl + i*64 + jq*16 + q*4);
        float sv = fb_s[i];
        for (int m=0;m<64;++m){
            float kim = aug[m*132 + 64 + i] * rds[m];
#pragma unroll
            for (int q=0;q<4;++q){
                float4 pv = *(const float4*)(Pl + m*64 + jq*16 + q*4);
                m4[q].x -= kim*pv.x; m4[q].y -= kim*pv.y; m4[q].z -= kim*pv.z; m4[q].w -= kim*pv.w;
            }
            sv -= kim * fb_s[m];
        }
        size_t base = ((size_t)b << 12) + (size_t)i*64;
#pragma unroll
        for (int q=0;q<4;++q) *(float4*)(Mg + base + jq*16 + q*4) = m4[q];
        if (jq == 0) v0g[b*64 + i] = sv;
    }
}

// ---------------------------------------------------------------------------
// yhat = M.h + K.x0 + v0 (fcf folded into M,v0); writes PADDED yhat + row sums.
// grid (64 rows, 8 b), block 256: pj = tid&15 (4 px), dgp = tid>>4 (4 d).
__global__ __launch_bounds__(256) void k_apply(int t, const float* __restrict__ hf_p,
                                               const float* __restrict__ x0,
                                               const float* __restrict__ Kg, const float* __restrict__ Mg,
                                               const float* __restrict__ v0g,
                                               float* __restrict__ yhat_p, float* __restrict__ featpart){
    __shared__ __align__(16) float kt[4160];   // kt[j*65 + i] = K[i][j]
    __shared__ __align__(16) float mt[4160];   // mt[j*65 + i] = M[i][j]
    const int row = blockIdx.x;
    const int b   = blockIdx.y;
    const int tid = threadIdx.x;
    const int pj = tid & 15, dgp = tid >> 4;

    for (int r = tid; r < 4096; r += 256){
        int i = r >> 6, j = r & 63;
        kt[j*65 + i] = Kg[((size_t)b << 12) + r];
        mt[j*65 + i] = Mg[((size_t)b << 12) + r];
    }
    __syncthreads();

    const int px0 = pj*4;
    const int d0  = dgp*4;
    float4 acc[4];
#pragma unroll
    for (int i=0;i<4;i++) acc[i] = make_float4(0.f,0.f,0.f,0.f);

    for (int j = 0; j < 64; ++j){
        float4 xv = *(const float4*)(x0 + (((size_t)(b*64 + j)) << 12) + row*64 + px0);
        float4 hv = *(const float4*)(hf_p + (((size_t)(b*64 + j))*66 + row + 1)*72 + px0 + 4);
        const float* kr = kt + j*65 + d0;
        const float* mr = mt + j*65 + d0;
#pragma unroll
        for (int il=0; il<4; ++il){
            FMA4(acc[il], kr[il], xv.x, xv.y, xv.z, xv.w);
            FMA4(acc[il], mr[il], hv.x, hv.y, hv.z, hv.w);
        }
    }
    float ls[4];
#pragma unroll
    for (int il=0;il<4;++il){
        int d = d0 + il;
        float v0v = v0g[b*64 + d];
        float4 o = acc[il];
        o.x += v0v; o.y += v0v; o.z += v0v; o.w += v0v;
        *(float4*)(yhat_p + (((size_t)(b*64 + d))*66 + row + 1)*72 + px0 + 4) = o;
        ls[il] = o.x + o.y + o.z + o.w;
    }
    __syncthreads();   // kt/mt reads done; reuse kt as reduction scratch
#pragma unroll
    for (int il=0;il<4;++il) kt[pj*65 + d0 + il] = ls[il];
    __syncthreads();
    if (tid < 64){
        float s = 0.f;
#pragma unroll
        for (int q=0;q<16;++q) s += kt[q*65 + tid];
        featpart[(((size_t)((t*8 + b)*64 + row)) << 6) + tid] = s;
    }
}

// ---------------------------------------------------------------------------
__global__ __launch_bounds__(64) void k_head(const float* __restrict__ featpart,
                                             const float* __restrict__ fc_w, const float* __restrict__ fc_b,
                                             const float* __restrict__ fco_w, const float* __restrict__ fco_b,
                                             const float* __restrict__ fca_w, const float* __restrict__ fca_b,
                                             float* __restrict__ out){
    const int bt = blockIdx.x;
    const int b = bt >> 4, t = bt & 15;
    __shared__ float fs[64];
    const int i = threadIdx.x;
    float s = 0.f;
    for (int row=0;row<64;row++) s += featpart[(((size_t)((t*8 + b)*64 + row)) << 6) + i];
    fs[i] = s * (1.f/4096.f);
    __syncthreads();
    float a = fc_b[i];
    for (int e=0;e<64;e++) a += fc_w[i*64+e]*fs[e];
    a = fmaxf(a, 0.f);
    float po = a * fco_w[i];
    float pa = a * fca_w[i];
    for (int off=32; off; off >>= 1){ po += __shfl_down(po, off); pa += __shfl_down(pa, off); }
    if (i == 0){
        out[bt]       = po + fco_b[0];
        out[128 + bt] = pa + fca_b[0];
    }
}

// ---------------------------------------------------------------------------
extern "C" void kernel_launch(void* const* d_in, const int* in_sizes, int n_in,
                              void* d_out, int out_size, void* d_ws, size_t ws_size,
                              hipStream_t stream){
    const float* x       = (const float*)d_in[0];
    const float* proj_w  = (const float*)d_in[1];
    const float* bn_g    = (const float*)d_in[2];
    const float* bn_b    = (const float*)d_in[3];
    const float* clstm_w = (const float*)d_in[4];
    const float* clstm_b = (const float*)d_in[5];
    const float* lq_wih  = (const float*)d_in[6];
    const float* lq_whh  = (const float*)d_in[7];
    const float* lq_bih  = (const float*)d_in[8];
    const float* lq_bhh  = (const float*)d_in[9];
    const float* lr_wih  = (const float*)d_in[10];
    const float* lr_whh  = (const float*)d_in[11];
    const float* lr_bih  = (const float*)d_in[12];
    const float* lr_bhh  = (const float*)d_in[13];
    const float* fcf_w   = (const float*)d_in[14];
    const float* fcf_b   = (const float*)d_in[15];
    const float* fcF_w   = (const float*)d_in[16];
    const float* fcF_b   = (const float*)d_in[17];
    const float* fcQ_w   = (const float*)d_in[18];
    const float* fcQ_b   = (const float*)d_in[19];
    const float* fcR_w   = (const float*)d_in[20];
    const float* fcR_b   = (const float*)d_in[21];
    const float* P_init  = (const float*)d_in[22];
    const float* fc_w    = (const float*)d_in[23];
    const float* fc_b    = (const float*)d_in[24];
    const float* fco_w   = (const float*)d_in[25];
    const float* fco_b   = (const float*)d_in[26];
    const float* fca_w   = (const float*)d_in[27];
    const float* fca_b   = (const float*)d_in[28];
    float* out = (float*)d_out;
    float* ws  = (float*)d_ws;

    const size_t PF    = 2433024;        // 8*64*66*72 padded field
    const size_t FIELD = 2097152;        // 8*64*4096
    float* yhat_p = ws;                  // PF
    float* hfA_p  = ws + PF;             // PF
    float* hfB_p  = ws + 2*PF;           // PF
    float* cf     = ws + 3*PF;           // FIELD  (zero-span = 3*PF + FIELD)
    float* x0     = cf + FIELD;          // FIELD
    float* w5     = x0 + FIELD;          // 294912
    float* psum   = w5 + 294912;         // 131072
    float* psumsq = psum + 131072;       // 131072
    float* scale  = psumsq + 131072;     // 64
    float* shift  = scale + 64;          // 64
    float* xmean  = shift + 64;          // 8192
    float* hfpart = xmean + 8192;        // 32768
    float* featpart = hfpart + 32768;    // 524288 (16 t x 8 b x 64 rows x 64 d)
    float* hQ     = featpart + 524288;   // 512
    float* cQ     = hQ + 512;
    float* hR     = cQ + 512;
    float* cR     = hR + 512;
    float* Pg     = cR + 512;            // 32768
    float* Kg     = Pg + 32768;          // 32768
    float* Mg     = Kg + 32768;          // 32768
    float* v0g    = Mg + 32768;          // 512

    hipLaunchKernelGGL(k_w5, dim3(1152), dim3(256), 0, stream, clstm_w, w5);
    hipLaunchKernelGGL(k_proj, dim3(16,128), dim3(256), 0, stream, x, proj_w, x0, psum, psumsq);
    hipLaunchKernelGGL(k_bnfinal, dim3(1), dim3(64), 0, stream, psum, psumsq, bn_g, bn_b, scale, shift, xmean);
    hipLaunchKernelGGL(k_zero, dim3(9176), dim3(256), 0, stream, ws);   // yhat_p|hfA_p|hfB_p|cf
    hipLaunchKernelGGL(k_init, dim3(8192), dim3(256), 0, stream, scale, shift, x0, yhat_p, P_init, Pg, hQ, cQ, hR, cR);

    for (int t = 0; t < 16; ++t){
        float* hf_in  = (t & 1) ? hfB_p : hfA_p;
        float* hf_out = (t & 1) ? hfA_p : hfB_p;
        hipLaunchKernelGGL(k_conv, dim3(64,2,8), dim3(512), 0, stream,
                           yhat_p, hf_in, hf_out, cf, w5, clstm_b, hfpart);
        hipLaunchKernelGGL(k_small, dim3(8), dim3(256), 0, stream, t,
                           hfpart, xmean, fcf_w, fcf_b, fcF_w, fcF_b,
                           lq_wih, lq_whh, lq_bih, lq_bhh,
                           lr_wih, lr_whh, lr_bih, lr_bhh,
                           fcQ_w, fcQ_b, fcR_w, fcR_b,
                           hQ, cQ, hR, cR, Pg, Kg, Mg, v0g);
        hipLaunchKernelGGL(k_apply, dim3(64,8), dim3(256), 0, stream, t,
                           hf_out, x0, Kg, Mg, v0g, yhat_p, featpart);
    }
    hipLaunchKernelGGL(k_head, dim3(128), dim3(64), 0, stream,
                       featpart, fc_w, fc_b, fco_w, fco_b, fca_w, fca_b, out);
}